// Round 6
// baseline (246.437 us; speedup 1.0000x reference)
//
#include <hip/hip_runtime.h>

#define B_ 1024
#define S_ 256
#define D_ 128
#define K_ 26

// ---------------- Kernel 1: emissions E[b][t][k] = dot(X[b][t], W[k]) ----------------
__global__ __launch_bounds__(256, 2) void emis_kernel(
    const float* __restrict__ X, const float* __restrict__ W, float* __restrict__ E)
{
  __shared__ float xt[64][132];
  const int tid = threadIdx.x;
  const int b   = blockIdx.x >> 2;
  const int r0  = (blockIdx.x & 3) << 6;

  {
    const float4* Xs = reinterpret_cast<const float4*>(X + ((size_t)b * S_ + r0) * D_);
#pragma unroll
    for (int it = 0; it < 8; ++it) {
      int i = it * 256 + tid;
      float4 v = Xs[i];
      int row = i >> 5, col = (i & 31) << 2;
      *reinterpret_cast<float4*>(&xt[row][col]) = v;
    }
  }
  __syncthreads();

  const int l = tid & 63;
  const int g = __builtin_amdgcn_readfirstlane(tid >> 6);
  const int k0 = (g < 2) ? 7 * g : 6 * g + 2;
  const int kn = (g < 2) ? 7 : 6;

  float acc[7][4];
#pragma unroll
  for (int kk = 0; kk < 7; ++kk)
#pragma unroll
    for (int c = 0; c < 4; ++c) acc[kk][c] = 0.f;

#pragma unroll
  for (int dc = 0; dc < 16; ++dc) {
    float4 a0 = *reinterpret_cast<const float4*>(&xt[l][dc * 8]);
    float4 a1 = *reinterpret_cast<const float4*>(&xt[l][dc * 8 + 4]);
    float xv[8] = {a0.x, a0.y, a0.z, a0.w, a1.x, a1.y, a1.z, a1.w};
#pragma unroll
    for (int kk = 0; kk < 7; ++kk) {
      int k = k0 + kk; k = (k > K_ - 1) ? (K_ - 1) : k;
      const float* wr = W + k * D_ + dc * 8;
#pragma unroll
      for (int dd = 0; dd < 8; ++dd)
        acc[kk][dd & 3] = fmaf(xv[dd], wr[dd], acc[kk][dd & 3]);
    }
  }

  float* eb = E + ((size_t)b * S_ + r0 + l) * K_ + k0;
#pragma unroll
  for (int kk = 0; kk < 7; ++kk)
    if (kk < kn)
      eb[kk] = (acc[kk][0] + acc[kk][1]) + (acc[kk][2] + acc[kk][3]);
}

// -------- Kernel 2: Viterbi, TWO chains per wave, packed LDS gather ------------------
// Lane j owns destination state j for BOTH chains (same tc column). Per iteration:
// unpack gathered deltas -> two add+max3-trees -> write packed (dA,dB) -> issue 14
// uniform b128 gather reads (latency hidden under the two eq-scans) -> bp write.
__global__ __launch_bounds__(64, 1) void viterbi2_kernel(
    const float* __restrict__ E, const float* __restrict__ Tr, int* __restrict__ out)
{
  __shared__ float2 ds2[28];                   // packed (deltaA, deltaB) per state
  __shared__ unsigned short bp2[K_][258];      // idxA | idxB<<8, per [state][t]
  __shared__ unsigned char spec2[K_][130][2];  // speculative paths, per chain
  __shared__ int path2[2][S_];

  const int lane = threadIdx.x;
  const int jc   = (lane < K_) ? lane : (K_ - 1);
  const int cA   = blockIdx.x * 2;

  float tc[K_];
#pragma unroll
  for (int i = 0; i < K_; ++i) tc[i] = Tr[i * K_ + jc];

  const float* eA = E + (size_t)cA * (S_ * K_) + jc;
  const float* eB = eA + (size_t)(S_ * K_);

  float dA = eA[0], dB = eB[0];
  float evA1 = eA[K_], evA2 = eA[2 * K_];
  float evB1 = eB[K_], evB2 = eB[2 * K_];

  if (lane < 28) ds2[lane] = make_float2(0.f, 0.f);   // init pad entries
  if (lane < K_) ds2[lane] = make_float2(dA, dB);

  float4 raw[14];
  {
    const float4* p = reinterpret_cast<const float4*>(&ds2[0]);
#pragma unroll
    for (int q = 0; q < 14; ++q) raw[q] = p[q];       // uniform broadcast reads
  }

  for (int t = 1; t < S_; ++t) {
    // raw holds delta(t-1): raw[q] = (A[2q], B[2q], A[2q+1], B[2q+1])
    float vA[K_], vB[K_];
#pragma unroll
    for (int q = 0; q < 13; ++q) {
      vA[2 * q]     = raw[q].x + tc[2 * q];
      vB[2 * q]     = raw[q].y + tc[2 * q];
      vA[2 * q + 1] = raw[q].z + tc[2 * q + 1];
      vB[2 * q + 1] = raw[q].w + tc[2 * q + 1];
    }

    // value trees (exact max; depth 3 of max3)
    float mA[9], mB[9];
#pragma unroll
    for (int i = 0; i < 8; ++i) {
      mA[i] = fmaxf(fmaxf(vA[3 * i], vA[3 * i + 1]), vA[3 * i + 2]);
      mB[i] = fmaxf(fmaxf(vB[3 * i], vB[3 * i + 1]), vB[3 * i + 2]);
    }
    mA[8] = fmaxf(vA[24], vA[25]);
    mB[8] = fmaxf(vB[24], vB[25]);
    float bestA = fmaxf(fmaxf(fmaxf(mA[0], mA[1]), mA[2]),
                  fmaxf(fmaxf(mA[3], mA[4]), mA[5]));
    bestA = fmaxf(bestA, fmaxf(fmaxf(mA[6], mA[7]), mA[8]));
    float bestB = fmaxf(fmaxf(fmaxf(mB[0], mB[1]), mB[2]),
                  fmaxf(fmaxf(mB[3], mB[4]), mB[5]));
    bestB = fmaxf(bestB, fmaxf(fmaxf(mB[6], mB[7]), mB[8]));

    // advance deltas (same op order as reference: max + e)
    dA = bestA + evA1;  evA1 = evA2;
    dB = bestB + evB1;  evB1 = evB2;
    int tn = (t + 2 < S_) ? (t + 2) : (S_ - 1);
    evA2 = eA[(size_t)tn * K_];
    evB2 = eB[(size_t)tn * K_];

    // publish delta(t) and issue next gather; latency hidden by eq-scans below
    if (lane < K_) ds2[lane] = make_float2(dA, dB);
    {
      const float4* p = reinterpret_cast<const float4*>(&ds2[0]);
#pragma unroll
      for (int q = 0; q < 14; ++q) raw[q] = p[q];
    }

    // exact first-argmax (ties -> lowest i, == jnp.argmax)
    int cAi[K_], cBi[K_];
#pragma unroll
    for (int i = 0; i < K_; ++i) {
      cAi[i] = (vA[i] == bestA) ? i : 63;
      cBi[i] = (vB[i] == bestB) ? i : 63;
    }
    int qA[9], qB[9];
#pragma unroll
    for (int i = 0; i < 8; ++i) {
      int a = cAi[3 * i] < cAi[3 * i + 1] ? cAi[3 * i] : cAi[3 * i + 1];
      qA[i] = a < cAi[3 * i + 2] ? a : cAi[3 * i + 2];
      int b = cBi[3 * i] < cBi[3 * i + 1] ? cBi[3 * i] : cBi[3 * i + 1];
      qB[i] = b < cBi[3 * i + 2] ? b : cBi[3 * i + 2];
    }
    qA[8] = cAi[24] < cAi[25] ? cAi[24] : cAi[25];
    qB[8] = cBi[24] < cBi[25] ? cBi[24] : cBi[25];
    int rA0 = qA[0] < qA[1] ? qA[0] : qA[1]; rA0 = rA0 < qA[2] ? rA0 : qA[2];
    int rA1 = qA[3] < qA[4] ? qA[3] : qA[4]; rA1 = rA1 < qA[5] ? rA1 : qA[5];
    int rA2 = qA[6] < qA[7] ? qA[6] : qA[7]; rA2 = rA2 < qA[8] ? rA2 : qA[8];
    int idxA = rA0 < rA1 ? rA0 : rA1; idxA = idxA < rA2 ? idxA : rA2;
    int rB0 = qB[0] < qB[1] ? qB[0] : qB[1]; rB0 = rB0 < qB[2] ? rB0 : qB[2];
    int rB1 = qB[3] < qB[4] ? qB[3] : qB[4]; rB1 = rB1 < qB[5] ? rB1 : qB[5];
    int rB2 = qB[6] < qB[7] ? qB[6] : qB[7]; rB2 = rB2 < qB[8] ? rB2 : qB[8];
    int idxB = rB0 < rB1 ? rB0 : rB1; idxB = idxB < rB2 ? idxB : rB2;

    if (lane < K_) bp2[lane][t] = (unsigned short)(idxA | (idxB << 8));
  }

  // final first-argmax for both chains (raw now holds delta(255), uniform on all lanes)
  int lastA, lastB;
  {
    float vA[K_], vB[K_];
#pragma unroll
    for (int q = 0; q < 13; ++q) {
      vA[2 * q] = raw[q].x;  vB[2 * q] = raw[q].y;
      vA[2 * q + 1] = raw[q].z;  vB[2 * q + 1] = raw[q].w;
    }
    float bA = vA[0], bB = vB[0];
#pragma unroll
    for (int i = 1; i < K_; ++i) { bA = fmaxf(bA, vA[i]); bB = fmaxf(bB, vB[i]); }
    int iA = 63, iB = 63;
#pragma unroll
    for (int i = K_ - 1; i >= 0; --i) {
      iA = (vA[i] == bA) ? i : iA;
      iB = (vB[i] == bB) ? i : iB;
    }
    lastA = iA; lastB = iB;
  }

  // backtrack, both chains in parallel lane groups (single wave -> no barriers).
  // chain = lane>=32; sl<26: speculative walkers over t=128..1; sl==26: real walker.
  {
    const int chain = (lane >= 32) ? 1 : 0;
    const int sl    = lane & 31;
    const bool is_spec = (sl < K_);
    const bool is_real = (sl == K_);
    int last = chain ? lastB : lastA;
    int c = is_spec ? sl : last;
    for (int k = 0; k < 128; ++k) {
      int t = is_spec ? (128 - k) : (255 - k);
      bool act = is_spec || (is_real && k <= 126);
      if (act) {
        c = (bp2[c][t] >> (chain * 8)) & 0xff;
        if (is_spec) spec2[sl][t - 1][chain] = (unsigned char)c;
        else if (t >= 129) path2[chain][t - 1] = c;   // covers 128..254
      }
    }
    if (is_real) path2[chain][S_ - 1] = last;
  }

  // stitch lower half from the realized state at t=128
  {
    int sA = path2[0][128];
    int sB = path2[1][128];
#pragma unroll
    for (int q = 0; q < 2; ++q) {
      int t = q * 64 + lane;
      path2[0][t] = (int)spec2[sA][t][0];
      path2[1][t] = (int)spec2[sB][t][1];
    }
  }

  int* oA = out + (size_t)cA * S_;
  int* oB = oA + S_;
#pragma unroll
  for (int q = 0; q < 4; ++q) {
    oA[q * 64 + lane] = path2[0][q * 64 + lane];
    oB[q * 64 + lane] = path2[1][q * 64 + lane];
  }
}

extern "C" void kernel_launch(void* const* d_in, const int* in_sizes, int n_in,
                              void* d_out, int out_size, void* d_ws, size_t ws_size,
                              hipStream_t stream) {
  (void)in_sizes; (void)n_in; (void)out_size; (void)ws_size;
  const float* X  = (const float*)d_in[0];
  const float* W  = (const float*)d_in[1];
  const float* Tr = (const float*)d_in[2];
  float* E = (float*)d_ws;             // needs B*S*K*4 = 27,262,976 B of scratch
  int* outp = (int*)d_out;

  emis_kernel<<<B_ * 4, 256, 0, stream>>>(X, W, E);
  viterbi2_kernel<<<B_ / 2, 64, 0, stream>>>(E, Tr, outp);
}

// Round 8
// 178.788 us; speedup vs baseline: 1.3784x; 1.3784x over previous
//
#include <hip/hip_runtime.h>

#define B_ 1024
#define S_ 256
#define D_ 128
#define K_ 26

// ---------------- Kernel 1: emissions E[b][t][k] = dot(X[b][t], W[k]) ----------------
__global__ __launch_bounds__(256, 2) void emis_kernel(
    const float* __restrict__ X, const float* __restrict__ W, float* __restrict__ E)
{
  __shared__ float xt[64][132];
  const int tid = threadIdx.x;
  const int b   = blockIdx.x >> 2;
  const int r0  = (blockIdx.x & 3) << 6;

  {
    const float4* Xs = reinterpret_cast<const float4*>(X + ((size_t)b * S_ + r0) * D_);
#pragma unroll
    for (int it = 0; it < 8; ++it) {
      int i = it * 256 + tid;
      float4 v = Xs[i];
      int row = i >> 5, col = (i & 31) << 2;
      *reinterpret_cast<float4*>(&xt[row][col]) = v;
    }
  }
  __syncthreads();

  const int l = tid & 63;
  const int g = __builtin_amdgcn_readfirstlane(tid >> 6);
  const int k0 = (g < 2) ? 7 * g : 6 * g + 2;
  const int kn = (g < 2) ? 7 : 6;

  float acc[7][4];
#pragma unroll
  for (int kk = 0; kk < 7; ++kk)
#pragma unroll
    for (int c = 0; c < 4; ++c) acc[kk][c] = 0.f;

#pragma unroll
  for (int dc = 0; dc < 16; ++dc) {
    float4 a0 = *reinterpret_cast<const float4*>(&xt[l][dc * 8]);
    float4 a1 = *reinterpret_cast<const float4*>(&xt[l][dc * 8 + 4]);
    float xv[8] = {a0.x, a0.y, a0.z, a0.w, a1.x, a1.y, a1.z, a1.w};
#pragma unroll
    for (int kk = 0; kk < 7; ++kk) {
      int k = k0 + kk; k = (k > K_ - 1) ? (K_ - 1) : k;
      const float* wr = W + k * D_ + dc * 8;
#pragma unroll
      for (int dd = 0; dd < 8; ++dd)
        acc[kk][dd & 3] = fmaf(xv[dd], wr[dd], acc[kk][dd & 3]);
    }
  }

  float* eb = E + ((size_t)b * S_ + r0 + l) * K_ + k0;
#pragma unroll
  for (int kk = 0; kk < 7; ++kk)
    if (kk < kn)
      eb[kk] = (acc[kk][0] + acc[kk][1]) + (acc[kk][2] + acc[kk][3]);
}

// -------- Kernel 2: Viterbi, one chain/wave, E fully in LDS, zero global loads in loop
// Ordering discipline (r7 failed without it): __syncthreads() after staging;
// explicit "s_waitcnt lgkmcnt(0)" + compiler memory fence between the delta
// publish (ds_write) and the broadcast gather (ds_read_b128) each step.
__global__ __launch_bounds__(64, 1) void viterbi_kernel(
    const float* __restrict__ E, const float* __restrict__ Tr, int* __restrict__ out)
{
  __shared__ __align__(16) float e_lds[S_ * K_];   // 26624 B
  __shared__ __align__(16) float pub[28];          // published delta vector
  __shared__ unsigned char bp[K_][260];
  __shared__ unsigned char spec[K_][132];
  __shared__ int path_s[S_];

  const int lane = threadIdx.x;
  const int jc   = (lane < K_) ? lane : (K_ - 1);
  const int b    = blockIdx.x;

  float tc[K_];
#pragma unroll
  for (int i = 0; i < K_; ++i) tc[i] = Tr[i * K_ + jc];

  // ---- stage E[b] to LDS (26 float4/lane, batched in two halves)
  {
    const float4* src = reinterpret_cast<const float4*>(E + (size_t)b * (S_ * K_));
    float4* dst = reinterpret_cast<float4*>(e_lds);
#pragma unroll
    for (int half = 0; half < 2; ++half) {
      float4 tmp[13];
#pragma unroll
      for (int i = 0; i < 13; ++i) tmp[i] = src[(half * 13 + i) * 64 + lane];
#pragma unroll
      for (int i = 0; i < 13; ++i) dst[(half * 13 + i) * 64 + lane] = tmp[i];
    }
  }
  __syncthreads();                                  // staging visible to all lanes

  // t = 0 publish + first gather
  float delta = e_lds[jc];
  if (lane < 28) pub[lane] = -3.4e38f;
  if (lane < K_) pub[lane] = delta;
  asm volatile("s_waitcnt lgkmcnt(0)" ::: "memory");

  float4 raw[7];
  {
    const float4* p = reinterpret_cast<const float4*>(pub);
#pragma unroll
    for (int q = 0; q < 7; ++q) raw[q] = p[q];      // uniform broadcast reads
  }

  float ev1 = e_lds[K_ + jc];
  float ev2 = e_lds[2 * K_ + jc];

  for (int t = 1; t < S_; ++t) {
    // raw holds delta(t-1)
    float v[K_ + 2];
#pragma unroll
    for (int q = 0; q < 7; ++q) {
      v[4 * q + 0] = raw[q].x;
      v[4 * q + 1] = raw[q].y;
      v[4 * q + 2] = raw[q].z;
      v[4 * q + 3] = raw[q].w;
    }
#pragma unroll
    for (int i = 0; i < K_; ++i) v[i] += tc[i];

    // value path: max3 tree (exact)
    float m[9];
#pragma unroll
    for (int i = 0; i < 8; ++i) m[i] = fmaxf(fmaxf(v[3 * i], v[3 * i + 1]), v[3 * i + 2]);
    m[8] = fmaxf(v[24], v[25]);
    float n0 = fmaxf(fmaxf(m[0], m[1]), m[2]);
    float n1 = fmaxf(fmaxf(m[3], m[4]), m[5]);
    float n2 = fmaxf(fmaxf(m[6], m[7]), m[8]);
    float best = fmaxf(fmaxf(n0, n1), n2);

    // advance delta (same op order as reference: max + e); ev from LDS, reg-prefetched
    float ev = ev1; ev1 = ev2;
    int tn = (t + 2 < S_) ? (t + 2) : (S_ - 1);
    ev2 = e_lds[tn * K_ + jc];
    delta = best + ev;

    // publish delta(t), drain the write, then issue next gather; the eq-scan
    // below hides the gather's read latency.
    if (lane < K_) pub[lane] = delta;
    asm volatile("s_waitcnt lgkmcnt(0)" ::: "memory");
    {
      const float4* p = reinterpret_cast<const float4*>(pub);
#pragma unroll
      for (int q = 0; q < 7; ++q) raw[q] = p[q];
    }

    // argmax path (off critical path): first i with v[i]==best
    int c[K_];
#pragma unroll
    for (int i = 0; i < K_; ++i) c[i] = (v[i] == best) ? i : 63;
    int q9[9];
#pragma unroll
    for (int i = 0; i < 8; ++i) {
      int a = c[3 * i] < c[3 * i + 1] ? c[3 * i] : c[3 * i + 1];
      q9[i] = a < c[3 * i + 2] ? a : c[3 * i + 2];
    }
    q9[8] = c[24] < c[25] ? c[24] : c[25];
    int r0 = q9[0] < q9[1] ? q9[0] : q9[1]; r0 = r0 < q9[2] ? r0 : q9[2];
    int r1 = q9[3] < q9[4] ? q9[3] : q9[4]; r1 = r1 < q9[5] ? r1 : q9[5];
    int r2 = q9[6] < q9[7] ? q9[6] : q9[7]; r2 = r2 < q9[8] ? r2 : q9[8];
    int idx = r0 < r1 ? r0 : r1; idx = idx < r2 ? idx : r2;

    if (lane < K_) bp[lane][t] = (unsigned char)idx;
  }

  // final first-argmax over delta(255) (raw holds it, uniform on all lanes)
  int last;
  {
    float v[K_];
#pragma unroll
    for (int q = 0; q < 7; ++q) {
      if (4 * q + 0 < K_) v[4 * q + 0] = raw[q].x;
      if (4 * q + 1 < K_) v[4 * q + 1] = raw[q].y;
      if (4 * q + 2 < K_) v[4 * q + 2] = raw[q].z;
      if (4 * q + 3 < K_) v[4 * q + 3] = raw[q].w;
    }
    float bf = v[0];
#pragma unroll
    for (int i = 1; i < K_; ++i) bf = fmaxf(bf, v[i]);
    int iA = 63;
#pragma unroll
    for (int i = K_ - 1; i >= 0; --i) iA = (v[i] == bf) ? i : iA;
    last = iA;
  }

  __syncthreads();

  // backtrack: real chain (lane 63) t=255..129 concurrent with 26 speculative
  // chains (lanes 0..25) covering t=128..1 for every possible state@128.
  {
    int c = (lane < K_) ? lane : last;
    for (int k = 0; k < 128; ++k) {
      int t = (lane < K_) ? (128 - k) : (255 - k);
      bool act = (lane < K_) || (lane == 63 && k <= 126);
      if (act) {
        c = bp[c][t];
        if (lane < K_) spec[lane][t - 1] = (unsigned char)c;
        else if (t >= 129) path_s[t - 1] = c;   // covers 128..254
      }
    }
  }
  __syncthreads();

  {
    int sstar = path_s[128];
#pragma unroll
    for (int q2 = 0; q2 < 2; ++q2) {
      int t = q2 * 64 + lane;
      path_s[t] = (int)spec[sstar][t];
    }
    if (lane == 0) path_s[S_ - 1] = last;
  }
  __syncthreads();

  int* o = out + (size_t)b * S_;
#pragma unroll
  for (int q2 = 0; q2 < 4; ++q2) o[q2 * 64 + lane] = path_s[q2 * 64 + lane];
}

extern "C" void kernel_launch(void* const* d_in, const int* in_sizes, int n_in,
                              void* d_out, int out_size, void* d_ws, size_t ws_size,
                              hipStream_t stream) {
  (void)in_sizes; (void)n_in; (void)out_size; (void)ws_size;
  const float* X  = (const float*)d_in[0];
  const float* W  = (const float*)d_in[1];
  const float* Tr = (const float*)d_in[2];
  float* E = (float*)d_ws;             // needs B*S*K*4 = 27,262,976 B of scratch
  int* outp = (int*)d_out;

  emis_kernel<<<B_ * 4, 256, 0, stream>>>(X, W, E);
  viterbi_kernel<<<B_, 64, 0, stream>>>(E, Tr, outp);
}

// Round 9
// 177.241 us; speedup vs baseline: 1.3904x; 1.0087x over previous
//
#include <hip/hip_runtime.h>

#define B_ 1024
#define S_ 256
#define D_ 128
#define K_ 26

// ---------------- Kernel 1: emissions E[b][t][k] = dot(X[b][t], W[k]) ----------------
__global__ __launch_bounds__(256, 2) void emis_kernel(
    const float* __restrict__ X, const float* __restrict__ W, float* __restrict__ E)
{
  __shared__ float xt[64][132];
  const int tid = threadIdx.x;
  const int b   = blockIdx.x >> 2;
  const int r0  = (blockIdx.x & 3) << 6;

  {
    const float4* Xs = reinterpret_cast<const float4*>(X + ((size_t)b * S_ + r0) * D_);
#pragma unroll
    for (int it = 0; it < 8; ++it) {
      int i = it * 256 + tid;
      float4 v = Xs[i];
      int row = i >> 5, col = (i & 31) << 2;
      *reinterpret_cast<float4*>(&xt[row][col]) = v;
    }
  }
  __syncthreads();

  const int l = tid & 63;
  const int g = __builtin_amdgcn_readfirstlane(tid >> 6);
  const int k0 = (g < 2) ? 7 * g : 6 * g + 2;
  const int kn = (g < 2) ? 7 : 6;

  float acc[7][4];
#pragma unroll
  for (int kk = 0; kk < 7; ++kk)
#pragma unroll
    for (int c = 0; c < 4; ++c) acc[kk][c] = 0.f;

#pragma unroll
  for (int dc = 0; dc < 16; ++dc) {
    float4 a0 = *reinterpret_cast<const float4*>(&xt[l][dc * 8]);
    float4 a1 = *reinterpret_cast<const float4*>(&xt[l][dc * 8 + 4]);
    float xv[8] = {a0.x, a0.y, a0.z, a0.w, a1.x, a1.y, a1.z, a1.w};
#pragma unroll
    for (int kk = 0; kk < 7; ++kk) {
      int k = k0 + kk; k = (k > K_ - 1) ? (K_ - 1) : k;
      const float* wr = W + k * D_ + dc * 8;
#pragma unroll
      for (int dd = 0; dd < 8; ++dd)
        acc[kk][dd & 3] = fmaf(xv[dd], wr[dd], acc[kk][dd & 3]);
    }
  }

  float* eb = E + ((size_t)b * S_ + r0 + l) * K_ + k0;
#pragma unroll
  for (int kk = 0; kk < 7; ++kk)
    if (kk < kn)
      eb[kk] = (acc[kk][0] + acc[kk][1]) + (acc[kk][2] + acc[kk][3]);
}

// -------- Kernel 2: Viterbi, one chain/wave, E in LDS; drain covers only the publish
// write (ev prefetch + bp write issued AFTER the gather so the mandatory
// lgkmcnt(0) between publish and gather waits ~one write, not a read chain.
__global__ __launch_bounds__(64, 1) void viterbi_kernel(
    const float* __restrict__ E, const float* __restrict__ Tr, int* __restrict__ out)
{
  __shared__ __align__(16) float e_lds[S_ * K_];   // 26624 B
  __shared__ __align__(16) float pub[28];          // published delta vector
  __shared__ unsigned char bp[K_][260];
  __shared__ unsigned char spec[K_][132];
  __shared__ int path_s[S_];

  const int lane = threadIdx.x;
  const int jc   = (lane < K_) ? lane : (K_ - 1);
  const int b    = blockIdx.x;

  float tc[K_];
#pragma unroll
  for (int i = 0; i < K_; ++i) tc[i] = Tr[i * K_ + jc];

  // ---- stage E[b] to LDS (26 float4/lane, batched in two halves)
  {
    const float4* src = reinterpret_cast<const float4*>(E + (size_t)b * (S_ * K_));
    float4* dst = reinterpret_cast<float4*>(e_lds);
#pragma unroll
    for (int half = 0; half < 2; ++half) {
      float4 tmp[13];
#pragma unroll
      for (int i = 0; i < 13; ++i) tmp[i] = src[(half * 13 + i) * 64 + lane];
#pragma unroll
      for (int i = 0; i < 13; ++i) dst[(half * 13 + i) * 64 + lane] = tmp[i];
    }
  }
  __syncthreads();                                  // staging visible to all lanes

  // t = 0 publish + first gather
  float delta = e_lds[jc];
  if (lane < 28) pub[lane] = -3.4e38f;
  if (lane < K_) pub[lane] = delta;
  asm volatile("s_waitcnt lgkmcnt(0)" ::: "memory");

  float4 raw[7];
  {
    const float4* p = reinterpret_cast<const float4*>(pub);
#pragma unroll
    for (int q = 0; q < 7; ++q) raw[q] = p[q];      // uniform broadcast reads
  }
  float ev_cur = e_lds[K_ + jc];                    // e[1][jc], consumed at t=1

  for (int t = 1; t < S_; ++t) {
    // raw holds delta(t-1)
    float v[K_ + 2];
#pragma unroll
    for (int q = 0; q < 7; ++q) {
      v[4 * q + 0] = raw[q].x;
      v[4 * q + 1] = raw[q].y;
      v[4 * q + 2] = raw[q].z;
      v[4 * q + 3] = raw[q].w;
    }
#pragma unroll
    for (int i = 0; i < K_; ++i) v[i] += tc[i];

    // value path: max3 tree (exact)
    float m[9];
#pragma unroll
    for (int i = 0; i < 8; ++i) m[i] = fmaxf(fmaxf(v[3 * i], v[3 * i + 1]), v[3 * i + 2]);
    m[8] = fmaxf(v[24], v[25]);
    float n0 = fmaxf(fmaxf(m[0], m[1]), m[2]);
    float n1 = fmaxf(fmaxf(m[3], m[4]), m[5]);
    float n2 = fmaxf(fmaxf(m[6], m[7]), m[8]);
    float best = fmaxf(fmaxf(n0, n1), n2);

    // advance delta (same op order as reference: max + e)
    delta = best + ev_cur;

    // publish delta(t); drain (only this write is fresh); issue next gather
    if (lane < K_) pub[lane] = delta;
    asm volatile("s_waitcnt lgkmcnt(0)" ::: "memory");
    {
      const float4* p = reinterpret_cast<const float4*>(pub);
#pragma unroll
      for (int q = 0; q < 7; ++q) raw[q] = p[q];
    }

    // next-iter emission prefetch (read issued after gather; consumed next iter)
    int tn = (t + 1 < S_) ? (t + 1) : (S_ - 1);
    ev_cur = e_lds[tn * K_ + jc];

    // argmax path (fills the gather latency window): first i with v[i]==best
    int c[K_];
#pragma unroll
    for (int i = 0; i < K_; ++i) c[i] = (v[i] == best) ? i : 63;
    int q9[9];
#pragma unroll
    for (int i = 0; i < 8; ++i) {
      int a = c[3 * i] < c[3 * i + 1] ? c[3 * i] : c[3 * i + 1];
      q9[i] = a < c[3 * i + 2] ? a : c[3 * i + 2];
    }
    q9[8] = c[24] < c[25] ? c[24] : c[25];
    int r0 = q9[0] < q9[1] ? q9[0] : q9[1]; r0 = r0 < q9[2] ? r0 : q9[2];
    int r1 = q9[3] < q9[4] ? q9[3] : q9[4]; r1 = r1 < q9[5] ? r1 : q9[5];
    int r2 = q9[6] < q9[7] ? q9[6] : q9[7]; r2 = r2 < q9[8] ? r2 : q9[8];
    int idx = r0 < r1 ? r0 : r1; idx = idx < r2 ? idx : r2;

    if (lane < K_) bp[lane][t] = (unsigned char)idx;
  }

  // final first-argmax over delta(255) (raw holds it, uniform on all lanes)
  int last;
  {
    float v[K_];
#pragma unroll
    for (int q = 0; q < 7; ++q) {
      if (4 * q + 0 < K_) v[4 * q + 0] = raw[q].x;
      if (4 * q + 1 < K_) v[4 * q + 1] = raw[q].y;
      if (4 * q + 2 < K_) v[4 * q + 2] = raw[q].z;
      if (4 * q + 3 < K_) v[4 * q + 3] = raw[q].w;
    }
    float bf = v[0];
#pragma unroll
    for (int i = 1; i < K_; ++i) bf = fmaxf(bf, v[i]);
    int iA = 63;
#pragma unroll
    for (int i = K_ - 1; i >= 0; --i) iA = (v[i] == bf) ? i : iA;
    last = iA;
  }

  __syncthreads();

  // backtrack: real chain (lane 63) t=255..129 concurrent with 26 speculative
  // chains (lanes 0..25) covering t=128..1 for every possible state@128.
  {
    int c = (lane < K_) ? lane : last;
    for (int k = 0; k < 128; ++k) {
      int t = (lane < K_) ? (128 - k) : (255 - k);
      bool act = (lane < K_) || (lane == 63 && k <= 126);
      if (act) {
        c = bp[c][t];
        if (lane < K_) spec[lane][t - 1] = (unsigned char)c;
        else if (t >= 129) path_s[t - 1] = c;   // covers 128..254
      }
    }
  }
  __syncthreads();

  {
    int sstar = path_s[128];
#pragma unroll
    for (int q2 = 0; q2 < 2; ++q2) {
      int t = q2 * 64 + lane;
      path_s[t] = (int)spec[sstar][t];
    }
    if (lane == 0) path_s[S_ - 1] = last;
  }
  __syncthreads();

  int* o = out + (size_t)b * S_;
#pragma unroll
  for (int q2 = 0; q2 < 4; ++q2) o[q2 * 64 + lane] = path_s[q2 * 64 + lane];
}

extern "C" void kernel_launch(void* const* d_in, const int* in_sizes, int n_in,
                              void* d_out, int out_size, void* d_ws, size_t ws_size,
                              hipStream_t stream) {
  (void)in_sizes; (void)n_in; (void)out_size; (void)ws_size;
  const float* X  = (const float*)d_in[0];
  const float* W  = (const float*)d_in[1];
  const float* Tr = (const float*)d_in[2];
  float* E = (float*)d_ws;             // needs B*S*K*4 = 27,262,976 B of scratch
  int* outp = (int*)d_out;

  emis_kernel<<<B_ * 4, 256, 0, stream>>>(X, W, E);
  viterbi_kernel<<<B_, 64, 0, stream>>>(E, Tr, outp);
}